// Round 1
// baseline (238.110 us; speedup 1.0000x reference)
//
#include <hip/hip_runtime.h>

// FinePreprocess: B=2, D_F=128, Hf=240, Wf=320, L=4800 (Hc=60 x Wc=80),
// W_SZ=5, stride=4, D_C=256. M = in_sizes[6] (=3000).
// out = merged[2M][25][128] flat (tuple concat == full merged buffer).
//
// Decomposition:
//  prep:  CW[256][128]  = down_W^T @ W2^T   (W2 = merge_W[:,128:])
//         W1T[128][128] = W1^T              (W1 = merge_W[:,:128])
//         cbias[128]    = down_b @ W2^T + merge_b
//  t2:    t2[m][o] = c_row[m] @ CW + cbias           (w-invariant part)
//  fine:  out[m][w][o] = f_win[m][w][:] @ W1T[:][o] + t2[m][o]

#define HF 240
#define WF 320
#define HWF (HF * WF)
#define WC_GRID 80
#define LPOS 4800

__global__ __launch_bounds__(256) void prep_kernel(
    const float* __restrict__ down_W, const float* __restrict__ down_b,
    const float* __restrict__ merge_W, const float* __restrict__ merge_b,
    float* __restrict__ CW, float* __restrict__ W1T, float* __restrict__ cbias) {
  int idx = blockIdx.x * 256 + threadIdx.x;
  if (idx < 32768) {
    // CW[k][o] = sum_t down_W[t][k] * merge_W[o][128+t]
    int k = idx >> 7, o = idx & 127;
    float s = 0.f;
    #pragma unroll 4
    for (int t = 0; t < 128; ++t)
      s += down_W[t * 256 + k] * merge_W[o * 256 + 128 + t];
    CW[idx] = s;
  } else if (idx < 49152) {
    int i2 = idx - 32768;
    int c = i2 >> 7, o = i2 & 127;
    W1T[i2] = merge_W[o * 256 + c];  // W1T[c][o]
  } else if (idx < 49280) {
    int o = idx - 49152;
    float s = merge_b[o];
    #pragma unroll 4
    for (int t = 0; t < 128; ++t)
      s += down_b[t] * merge_W[o * 256 + 128 + t];
    cbias[o] = s;
  }
}

// 8 m-rows per block, 256 threads. t2[m][o] = crow[m] @ CW + cbias.
__global__ __launch_bounds__(256) void t2_kernel(
    const float* __restrict__ c0, const float* __restrict__ c1,
    const int* __restrict__ b_ids, const int* __restrict__ i_ids,
    const int* __restrict__ j_ids,
    const float* __restrict__ CW, const float* __restrict__ cbias,
    float* __restrict__ t2, int M) {
  __shared__ float crow[8][256];
  const int t = threadIdx.x;
  const int m0 = blockIdx.x * 8;
  const int M2 = 2 * M;
  #pragma unroll
  for (int it = 0; it < 8; ++it) {
    int m = m0 + it;
    float v = 0.f;
    if (m < M2) {
      int b, pos;
      const float* src;
      if (m < M) { b = b_ids[m]; pos = i_ids[m]; src = c0; }
      else       { b = b_ids[m - M]; pos = j_ids[m - M]; src = c1; }
      v = src[((size_t)b * LPOS + pos) * 256 + t];
    }
    crow[it][t] = v;
  }
  __syncthreads();
  const int o = t & 127, half = t >> 7;
  const int r0 = half * 4;
  float a0 = 0.f, a1 = 0.f, a2 = 0.f, a3 = 0.f;
  #pragma unroll 4
  for (int k = 0; k < 256; ++k) {
    float wv = CW[k * 128 + o];  // coalesced, L1/L2-hot
    a0 += crow[r0 + 0][k] * wv;
    a1 += crow[r0 + 1][k] * wv;
    a2 += crow[r0 + 2][k] * wv;
    a3 += crow[r0 + 3][k] * wv;
  }
  const float cb = cbias[o];
  if (m0 + r0 + 0 < M2) t2[(size_t)(m0 + r0 + 0) * 128 + o] = a0 + cb;
  if (m0 + r0 + 1 < M2) t2[(size_t)(m0 + r0 + 1) * 128 + o] = a1 + cb;
  if (m0 + r0 + 2 < M2) t2[(size_t)(m0 + r0 + 2) * 128 + o] = a2 + cb;
  if (m0 + r0 + 3 < M2) t2[(size_t)(m0 + r0 + 3) * 128 + o] = a3 + cb;
}

// One block per m (2M blocks), 256 threads.
// Stage f_win[25][128] in LDS, then out[w][o] = sum_c f[w][c]*W1T[c][o] + t2[o].
// Thread map: o = 2*(t&63) (float2 on W1T/out), w-group = t>>6 covers 7 w's.
__global__ __launch_bounds__(256) void fine_kernel(
    const float* __restrict__ f0, const float* __restrict__ f1,
    const int* __restrict__ b_ids, const int* __restrict__ i_ids,
    const int* __restrict__ j_ids,
    const float* __restrict__ W1T, const float* __restrict__ t2,
    float* __restrict__ out, int M) {
  __shared__ float fl[25][128];
  const int m = blockIdx.x;
  const int t = threadIdx.x;

  int b, pos;
  const float* src;
  if (m < M) { b = b_ids[m]; pos = i_ids[m]; src = f0; }
  else       { int mm = m - M; b = b_ids[mm]; pos = j_ids[mm]; src = f1; }
  const int hc = pos / WC_GRID, wc = pos - hc * WC_GRID;
  const int h0 = hc * 4 - 2, col0 = wc * 4 - 2;
  const float* base = src + (size_t)b * (128 * HWF);

  // Gather 25*128 = 3200 floats. idx = w*128 + c: lanes walk c (conflict-free
  // LDS writes); global reads are channel-strided gathers (L2/L3-resident).
  #pragma unroll
  for (int it = 0; it < 13; ++it) {
    int idx = it * 256 + t;
    if (idx < 3200) {
      int w = idx >> 7, c = idx & 127;
      int wr = w / 5;
      int hh = h0 + wr, cc = col0 + (w - wr * 5);
      float v = 0.f;
      if ((unsigned)hh < (unsigned)HF && (unsigned)cc < (unsigned)WF)
        v = base[(size_t)c * HWF + hh * WF + cc];
      fl[w][c] = v;
    }
  }
  __syncthreads();

  const int o = (t & 63) * 2;
  const int wbeg = (t >> 6) * 7;  // 0,7,14,21 ; last group has 4 w's
  float acc[7][2];
  #pragma unroll
  for (int j = 0; j < 7; ++j) { acc[j][0] = 0.f; acc[j][1] = 0.f; }

  for (int c = 0; c < 128; c += 4) {
    float2 wv0 = *(const float2*)&W1T[(c + 0) * 128 + o];
    float2 wv1 = *(const float2*)&W1T[(c + 1) * 128 + o];
    float2 wv2 = *(const float2*)&W1T[(c + 2) * 128 + o];
    float2 wv3 = *(const float2*)&W1T[(c + 3) * 128 + o];
    #pragma unroll
    for (int j = 0; j < 7; ++j) {
      int w = wbeg + j;
      if (w < 25) {
        float4 f4 = *(const float4*)&fl[w][c];  // ds_read_b128 broadcast
        acc[j][0] += f4.x * wv0.x + f4.y * wv1.x + f4.z * wv2.x + f4.w * wv3.x;
        acc[j][1] += f4.x * wv0.y + f4.y * wv1.y + f4.z * wv2.y + f4.w * wv3.y;
      }
    }
  }

  const float tb0 = t2[(size_t)m * 128 + o];
  const float tb1 = t2[(size_t)m * 128 + o + 1];
  #pragma unroll
  for (int j = 0; j < 7; ++j) {
    int w = wbeg + j;
    if (w < 25) {
      float2 r;
      r.x = acc[j][0] + tb0;
      r.y = acc[j][1] + tb1;
      *(float2*)&out[((size_t)m * 25 + w) * 128 + o] = r;
    }
  }
}

extern "C" void kernel_launch(void* const* d_in, const int* in_sizes, int n_in,
                              void* d_out, int out_size, void* d_ws, size_t ws_size,
                              hipStream_t stream) {
  const float* f0      = (const float*)d_in[0];
  const float* f1      = (const float*)d_in[1];
  const float* c0      = (const float*)d_in[2];
  const float* c1      = (const float*)d_in[3];
  // d_in[4] = hw0_f (240), d_in[5] = hw0_c (60) — shapes hardcoded
  const int*   b_ids   = (const int*)d_in[6];
  const int*   i_ids   = (const int*)d_in[7];
  const int*   j_ids   = (const int*)d_in[8];
  const float* down_W  = (const float*)d_in[9];
  const float* down_b  = (const float*)d_in[10];
  const float* merge_W = (const float*)d_in[11];
  const float* merge_b = (const float*)d_in[12];
  const int M = in_sizes[6];
  const int M2 = 2 * M;

  float* ws    = (float*)d_ws;
  float* CW    = ws;          // 256*128 = 32768
  float* W1T   = ws + 32768;  // 128*128 = 16384
  float* cbias = ws + 49152;  // 128
  float* t2    = ws + 49280;  // 2M*128

  prep_kernel<<<193, 256, 0, stream>>>(down_W, down_b, merge_W, merge_b,
                                       CW, W1T, cbias);
  t2_kernel<<<(M2 + 7) / 8, 256, 0, stream>>>(c0, c1, b_ids, i_ids, j_ids,
                                              CW, cbias, t2, M);
  fine_kernel<<<M2, 256, 0, stream>>>(f0, f1, b_ids, i_ids, j_ids,
                                      W1T, t2, (float*)d_out, M);
}

// Round 2
// 107.406 us; speedup vs baseline: 2.2169x; 2.2169x over previous
//
#include <hip/hip_runtime.h>

// FinePreprocess, MFMA version.
// B=2, D_F=128, Hf=240, Wf=320, L=4800 (60x80), W=5, stride=4, D_C=256, M=3000.
//
//  transpose: feat [b][c][h][w] f32 -> tmap [b][h*320+w][c] bf16  (coalesced both sides)
//  prep:      CW[256][128] = down_W^T @ W2^T (f32), cbias[128], W1bf[n][c] bf16 (=merge_W[:, :128])
//  t2:        t2[m][o] = c_row[m] @ CW + cbias   (f32, w-invariant term)
//  fine:      out[m][p][o] = sum_c win[p][c]*W1[o][c] + t2[m][o]  via mfma_f32_16x16x32_bf16
//             A (window rows) loaded global->reg directly in fragment layout from tmap;
//             B (W1^T) staged in LDS with XOR swizzle (T2) for conflict-free ds_read_b128.

#define HF 240
#define WF 320
#define HWF (HF * WF)
#define LPOS 4800

typedef short short8 __attribute__((ext_vector_type(8)));
typedef float f32x4 __attribute__((ext_vector_type(4)));

__device__ __forceinline__ unsigned short f2bf(float x) {
  union { float f; unsigned u; } v; v.f = x;
  unsigned r = v.u + 0x7FFF + ((v.u >> 16) & 1);  // RNE
  return (unsigned short)(r >> 16);
}

// ---------------- transpose + bf16 convert ----------------
// grid (1200, 4): y -> (tensor=y>>1, b=y&1); 64 pixels x 128 channels per block.
__global__ __launch_bounds__(256) void transpose_kernel(
    const float* __restrict__ f0, const float* __restrict__ f1,
    unsigned short* __restrict__ t0, unsigned short* __restrict__ t1) {
  __shared__ unsigned short tile[128][66];  // [c][pix], pad 66 (LDS-write conflict-free)
  const int t = threadIdx.x;
  const int hw0 = blockIdx.x * 64;
  const int map = blockIdx.y;
  const float* src = ((map >> 1) ? f1 : f0) + (size_t)(map & 1) * 128 * HWF;
  unsigned short* dst = ((map >> 1) ? t1 : t0) + (size_t)(map & 1) * HWF * 128;

  const int p0 = (t & 31) * 2;
  const int cg = t >> 5;  // 0..7
  #pragma unroll
  for (int ci = 0; ci < 16; ++ci) {
    int c = ci * 8 + cg;
    float2 v = *(const float2*)&src[(size_t)c * HWF + hw0 + p0];  // 256B/32 lanes
    ushort2 u;
    u.x = f2bf(v.x);
    u.y = f2bf(v.y);
    *(ushort2*)&tile[c][p0] = u;
  }
  __syncthreads();
  const int c4 = (t & 31) * 4;
  #pragma unroll
  for (int wi = 0; wi < 8; ++wi) {
    int p = wi * 8 + cg;
    ushort4 u;
    u.x = tile[c4 + 0][p];
    u.y = tile[c4 + 1][p];
    u.z = tile[c4 + 2][p];
    u.w = tile[c4 + 3][p];
    *(ushort4*)&dst[(size_t)(hw0 + p) * 128 + c4] = u;  // 8B/lane coalesced
  }
}

// ---------------- prep: CW, cbias, W1bf ----------------
__global__ __launch_bounds__(256) void prep_kernel(
    const float* __restrict__ down_W, const float* __restrict__ down_b,
    const float* __restrict__ merge_W, const float* __restrict__ merge_b,
    float* __restrict__ CW, float* __restrict__ cbias,
    unsigned short* __restrict__ W1bf) {
  int idx = blockIdx.x * 256 + threadIdx.x;
  if (idx < 32768) {
    int k = idx >> 7, o = idx & 127;  // CW[k][o] = sum_t down_W[t][k]*merge_W[o][128+t]
    float s = 0.f;
    #pragma unroll 4
    for (int t = 0; t < 128; ++t)
      s += down_W[t * 256 + k] * merge_W[o * 256 + 128 + t];
    CW[idx] = s;
  } else if (idx < 49152) {
    int i2 = idx - 32768;
    int n = i2 >> 7, c = i2 & 127;
    W1bf[i2] = f2bf(merge_W[n * 256 + c]);  // W1bf[n][c]
  } else if (idx < 49280) {
    int o = idx - 49152;
    float s = merge_b[o];
    #pragma unroll 4
    for (int t = 0; t < 128; ++t)
      s += down_b[t] * merge_W[o * 256 + 128 + t];
    cbias[o] = s;
  }
}

// ---------------- t2: coarse path (f32, proven) ----------------
__global__ __launch_bounds__(256) void t2_kernel(
    const float* __restrict__ c0, const float* __restrict__ c1,
    const int* __restrict__ b_ids, const int* __restrict__ i_ids,
    const int* __restrict__ j_ids,
    const float* __restrict__ CW, const float* __restrict__ cbias,
    float* __restrict__ t2, int M) {
  __shared__ float crow[8][256];
  const int t = threadIdx.x;
  const int m0 = blockIdx.x * 8;
  const int M2 = 2 * M;
  #pragma unroll
  for (int it = 0; it < 8; ++it) {
    int m = m0 + it;
    float v = 0.f;
    if (m < M2) {
      int b, pos;
      const float* src;
      if (m < M) { b = b_ids[m]; pos = i_ids[m]; src = c0; }
      else       { b = b_ids[m - M]; pos = j_ids[m - M]; src = c1; }
      v = src[((size_t)b * LPOS + pos) * 256 + t];
    }
    crow[it][t] = v;
  }
  __syncthreads();
  const int o = t & 127, half = t >> 7;
  const int r0 = half * 4;
  float a0 = 0.f, a1 = 0.f, a2 = 0.f, a3 = 0.f;
  #pragma unroll 4
  for (int k = 0; k < 256; ++k) {
    float wv = CW[k * 128 + o];
    a0 += crow[r0 + 0][k] * wv;
    a1 += crow[r0 + 1][k] * wv;
    a2 += crow[r0 + 2][k] * wv;
    a3 += crow[r0 + 3][k] * wv;
  }
  const float cb = cbias[o];
  if (m0 + r0 + 0 < M2) t2[(size_t)(m0 + r0 + 0) * 128 + o] = a0 + cb;
  if (m0 + r0 + 1 < M2) t2[(size_t)(m0 + r0 + 1) * 128 + o] = a1 + cb;
  if (m0 + r0 + 2 < M2) t2[(size_t)(m0 + r0 + 2) * 128 + o] = a2 + cb;
  if (m0 + r0 + 3 < M2) t2[(size_t)(m0 + r0 + 3) * 128 + o] = a3 + cb;
}

// ---------------- fine: MFMA ----------------
// 4 waves/block, 1 m per wave. A global->reg in frag layout; B in swizzled LDS.
__global__ __launch_bounds__(256) void fine_mfma_kernel(
    const unsigned short* __restrict__ t0, const unsigned short* __restrict__ t1,
    const int* __restrict__ b_ids, const int* __restrict__ i_ids,
    const int* __restrict__ j_ids,
    const unsigned short* __restrict__ W1bf, const float* __restrict__ t2,
    float* __restrict__ out, int M) {
  __shared__ unsigned short Bl[128 * 128];  // swizzled [n][c] bf16, 32KB
  const int t = threadIdx.x;

  // stage B: rows n of W1bf, 16B chunks, XOR swizzle kb ^ ((n&7)<<4)
  #pragma unroll
  for (int it = 0; it < 8; ++it) {
    int q = it * 256 + t;
    int n = q >> 4;
    int kb16 = (q & 15) * 16;
    short8 v = *(const short8*)&W1bf[n * 128 + (q & 15) * 8];
    int dstB = n * 256 + (kb16 ^ ((n & 7) << 4));
    *(short8*)((char*)Bl + dstB) = v;
  }

  const int wid = t >> 6, lane = t & 63;
  const int lr = lane & 15, lg = lane >> 4;
  const int m = blockIdx.x * 4 + wid;
  const int M2 = 2 * M;
  const bool active = (m < M2);

  // A-fragments: lane holds window[p = mt*16+lr][k = kk*32 + lg*8 + 0..7]
  short8 a[2][4];
  short8 az = {};
  if (active) {
    int b, pos;
    const unsigned short* tm;
    if (m < M) { b = b_ids[m]; pos = i_ids[m]; tm = t0; }
    else       { int mm = m - M; b = b_ids[mm]; pos = j_ids[mm]; tm = t1; }
    int hc = pos / 80, wc = pos - hc * 80;
    int h0 = hc * 4 - 2, w0 = wc * 4 - 2;
    #pragma unroll
    for (int mt = 0; mt < 2; ++mt) {
      int p = mt * 16 + lr;
      int pr = p / 5;
      int hh = h0 + pr, ww = w0 + (p - pr * 5);
      bool valid = (p < 25) && ((unsigned)hh < (unsigned)HF) && ((unsigned)ww < (unsigned)WF);
      if (!valid) { hh = 0; ww = 0; }
      const unsigned short* rowp =
          tm + (((size_t)b * HWF + (size_t)(hh * WF + ww)) << 7) + lg * 8;
      #pragma unroll
      for (int kk = 0; kk < 4; ++kk)
        a[mt][kk] = valid ? *(const short8*)(rowp + kk * 32) : az;
    }
  } else {
    #pragma unroll
    for (int mt = 0; mt < 2; ++mt)
      #pragma unroll
      for (int kk = 0; kk < 4; ++kk) a[mt][kk] = az;
  }

  __syncthreads();
  if (!active) return;

  f32x4 acc[2][8];
  #pragma unroll
  for (int mt = 0; mt < 2; ++mt)
    #pragma unroll
    for (int nt = 0; nt < 8; ++nt) {
      f32x4 z = {0.f, 0.f, 0.f, 0.f};
      acc[mt][nt] = z;
    }

  #pragma unroll
  for (int nt = 0; nt < 8; ++nt) {
    int n = nt * 16 + lr;
    int kbase = n * 256;
    int sw = (n & 7) << 4;
    short8 bfr[4];
    #pragma unroll
    for (int kk = 0; kk < 4; ++kk) {
      int kb = (kk * 64 + lg * 16) ^ sw;
      bfr[kk] = *(const short8*)((const char*)Bl + kbase + kb);
    }
    #pragma unroll
    for (int kk = 0; kk < 4; ++kk) {
      acc[0][nt] = __builtin_amdgcn_mfma_f32_16x16x32_bf16(a[0][kk], bfr[kk], acc[0][nt], 0, 0, 0);
      acc[1][nt] = __builtin_amdgcn_mfma_f32_16x16x32_bf16(a[1][kk], bfr[kk], acc[1][nt], 0, 0, 0);
    }
  }

  // epilogue: D row = mt*16 + lg*4 + j (skip rows >= 25), col = nt*16 + lr
  const float* t2row = t2 + (size_t)m * 128;
  float* orow = out + (size_t)m * 25 * 128;
  #pragma unroll
  for (int nt = 0; nt < 8; ++nt) {
    int o = nt * 16 + lr;
    float tv = t2row[o];
    #pragma unroll
    for (int mt = 0; mt < 2; ++mt) {
      #pragma unroll
      for (int j = 0; j < 4; ++j) {
        int r = mt * 16 + lg * 4 + j;
        if (r < 25) orow[r * 128 + o] = acc[mt][nt][j] + tv;
      }
    }
  }
}

extern "C" void kernel_launch(void* const* d_in, const int* in_sizes, int n_in,
                              void* d_out, int out_size, void* d_ws, size_t ws_size,
                              hipStream_t stream) {
  const float* f0      = (const float*)d_in[0];
  const float* f1      = (const float*)d_in[1];
  const float* c0      = (const float*)d_in[2];
  const float* c1      = (const float*)d_in[3];
  const int*   b_ids   = (const int*)d_in[6];
  const int*   i_ids   = (const int*)d_in[7];
  const int*   j_ids   = (const int*)d_in[8];
  const float* down_W  = (const float*)d_in[9];
  const float* down_b  = (const float*)d_in[10];
  const float* merge_W = (const float*)d_in[11];
  const float* merge_b = (const float*)d_in[12];
  const int M = in_sizes[6];
  const int M2 = 2 * M;

  // ws layout (bytes):
  //   CW     f32 [256*128]            @ 0          (131072 B)
  //   cbias  f32 [128]                @ 131072     (512 B)
  //   t2     f32 [2M*128]             @ 131584     (3,072,000 B @ M=3000)
  //   W1bf   bf16 [128*128]           @ aligned    (32768 B)
  //   t0     bf16 [2*76800*128]       (39,321,600 B)
  //   t1     bf16 [2*76800*128]       (39,321,600 B)
  char* wsb = (char*)d_ws;
  float* CW    = (float*)wsb;
  float* cbias = (float*)(wsb + 131072);
  float* t2    = (float*)(wsb + 131584);
  size_t t2_bytes = (size_t)M2 * 128 * 4;
  size_t off = 131584 + t2_bytes;
  off = (off + 255) & ~(size_t)255;
  unsigned short* W1bf = (unsigned short*)(wsb + off);
  off += 32768;
  unsigned short* t0 = (unsigned short*)(wsb + off);
  off += (size_t)2 * HWF * 128 * 2;
  unsigned short* t1 = (unsigned short*)(wsb + off);

  transpose_kernel<<<dim3(1200, 4), 256, 0, stream>>>(f0, f1, t0, t1);
  prep_kernel<<<193, 256, 0, stream>>>(down_W, down_b, merge_W, merge_b,
                                       CW, cbias, W1bf);
  t2_kernel<<<(M2 + 7) / 8, 256, 0, stream>>>(c0, c1, b_ids, i_ids, j_ids,
                                              CW, cbias, t2, M);
  fine_mfma_kernel<<<(M2 + 3) / 4, 256, 0, stream>>>(t0, t1, b_ids, i_ids, j_ids,
                                                     W1bf, t2, (float*)d_out, M);
}